// Round 3
// baseline (256.645 us; speedup 1.0000x reference)
//
#include <hip/hip_runtime.h>
#include <hip/hip_bf16.h>
#include <cstddef>
#include <cstdint>

// SelfAttn (SAGAN) — Round 8: barrier-free fattn. All MFMA operands (Q,K,G)
// loaded DIRECT from global as 16B/lane fragments (no global->LDS staging, no
// per-chunk barriers). Only P goes through LDS ([32][1024] bf16, one barrier).
// Batch->XCD affinity via blockIdx%8 so K/G stay L2-resident per XCD.

typedef __attribute__((ext_vector_type(8))) short short8;
typedef __attribute__((ext_vector_type(4))) float float4v;

namespace {
constexpr int kB = 8, kC = 512, kCK = 64, kCV = 256, kHW = 4096, kP = 1024;
constexpr int kNP = 384;  // packed projection width [theta|phi|g]
}

__device__ __forceinline__ void gll16(const void* g, void* l) {
  __builtin_amdgcn_global_load_lds((uint32_t __attribute__((address_space(1)))*)g,
                                   (uint32_t __attribute__((address_space(3)))*)l,
                                   16, 0, 0);
}
__device__ __forceinline__ float4v mfma16(short8 a, short8 b, float4v c) {
  return __builtin_amdgcn_mfma_f32_16x16x32_bf16(a, b, c, 0, 0, 0);
}
// bf16 tile row = 128B (8 octs of 16B), slot swizzle oct ^ (row&7)
__device__ __forceinline__ const short8* fragp(const char* tile, int row, int oct) {
  return (const short8*)(tile + row * 128 + ((oct ^ (row & 7)) * 16));
}

// pack weights: wAll[384][512] = [theta|phi|g]^T; woT[512][256]
__global__ __launch_bounds__(256) void k_pack_w(
    const float* __restrict__ wt, const float* __restrict__ wphi,
    const float* __restrict__ wg, const float* __restrict__ wo,
    __hip_bfloat16* __restrict__ wAll, __hip_bfloat16* __restrict__ woT) {
  int idx = blockIdx.x * 256 + threadIdx.x;  // 327680
  if (idx < 196608) {
    int n = idx >> 9, k = idx & 511;
    float v = (n < 64) ? wt[k * 64 + n]
            : (n < 128) ? wphi[k * 64 + (n - 64)]
                        : wg[k * 256 + (n - 128)];
    wAll[idx] = __float2bfloat16(v);
  } else {
    int t = idx - 196608;
    int n = t >> 8, k = t & 255;
    woT[t] = __float2bfloat16(wo[k * 512 + n]);
  }
}

// ---- proj: pgf[32768][384] = bf16(x) @ wAll^T, A fp32 read direct, tile 64x384 ----
__global__ __launch_bounds__(256) void k_proj(const float* __restrict__ x,
                                              const __hip_bfloat16* __restrict__ wAll,
                                              __hip_bfloat16* __restrict__ pgf) {
  __shared__ __align__(16) char smem[16384 + 49152];
  char* As = smem;           // fp32 [64 rows][16 sq of 16B], swizzle sq^(row&15)
  char* Bs = smem + 16384;   // bf16 [384 rows][8 oct], swizzle oct^(row&7)
  const int tid = threadIdx.x, wid = tid >> 6, lane = tid & 63;
  const int m = lane & 15, quad = lane >> 4;
  const int row0 = blockIdx.x * 64;
  const int wm = (wid >> 1) * 32, wn = (wid & 1) * 192;
  float4v acc[2][12] = {};
  for (int kc = 0; kc < 512; kc += 64) {
#pragma unroll
    for (int u = 0; u < 4; ++u) {  // A: region = 4 rows x 16 sq (1KB)
      const int r0 = (wid * 4 + u) * 4;
      const int row = r0 + (lane >> 4);
      const int sqg = (lane & 15) ^ (row & 15);
      gll16(x + (size_t)(row0 + row) * 512 + kc + sqg * 4, As + r0 * 256);
    }
#pragma unroll
    for (int u = 0; u < 12; ++u) {  // B: region = 8 rows x 8 oct (1KB)
      const int r0 = (wid * 12 + u) * 8;
      const int row = r0 + (lane >> 3);
      const int og = (lane & 7) ^ (row & 7);
      gll16(wAll + (size_t)row * 512 + kc + og * 8, Bs + r0 * 128);
    }
    __syncthreads();
#pragma unroll
    for (int kk = 0; kk < 64; kk += 32) {
      short8 af[2];
#pragma unroll
      for (int i = 0; i < 2; ++i) {
        const int row = wm + i * 16 + m;
        const int sq0 = (kk >> 2) + quad * 2;
        float4v lo = *(const float4v*)(As + row * 256 + ((sq0 ^ m) * 16));
        float4v hi = *(const float4v*)(As + row * 256 + (((sq0 + 1) ^ m) * 16));
        short8 a;
        a[0] = __builtin_bit_cast(short, __float2bfloat16(lo[0]));
        a[1] = __builtin_bit_cast(short, __float2bfloat16(lo[1]));
        a[2] = __builtin_bit_cast(short, __float2bfloat16(lo[2]));
        a[3] = __builtin_bit_cast(short, __float2bfloat16(lo[3]));
        a[4] = __builtin_bit_cast(short, __float2bfloat16(hi[0]));
        a[5] = __builtin_bit_cast(short, __float2bfloat16(hi[1]));
        a[6] = __builtin_bit_cast(short, __float2bfloat16(hi[2]));
        a[7] = __builtin_bit_cast(short, __float2bfloat16(hi[3]));
        af[i] = a;
      }
      const int oct = (kk >> 3) + quad;
#pragma unroll
      for (int j = 0; j < 12; ++j) {
        short8 bf = *fragp(Bs, wn + j * 16 + m, oct);
#pragma unroll
        for (int i = 0; i < 2; ++i) acc[i][j] = mfma16(af[i], bf, acc[i][j]);
      }
    }
    __syncthreads();
  }
#pragma unroll
  for (int i = 0; i < 2; ++i)
#pragma unroll
    for (int j = 0; j < 12; ++j)
#pragma unroll
      for (int r = 0; r < 4; ++r)
        pgf[(size_t)(row0 + wm + i * 16 + quad * 4 + r) * 384 + wn + j * 16 + m] =
            __float2bfloat16(acc[i][j][r]);
}

// phi_p[b][p][c] = max 2x2 of pgf[b,h,w,64+c]
__global__ __launch_bounds__(256) void k_pool_phi(const __hip_bfloat16* __restrict__ pg,
                                                  __hip_bfloat16* __restrict__ phi_p) {
  int idx = blockIdx.x * 256 + threadIdx.x;  // 524288
  int c = idx & 63;
  int p = (idx >> 6) & 1023;
  int b = idx >> 16;
  int ph = p >> 5, pw = p & 31;
  size_t base = ((size_t)b * 4096 + ph * 128 + pw * 2) * kNP + 64 + c;
  float v0 = __bfloat162float(pg[base]);
  float v1 = __bfloat162float(pg[base + kNP]);
  float v2 = __bfloat162float(pg[base + kNP * 64]);
  float v3 = __bfloat162float(pg[base + kNP * 64 + kNP]);
  phi_p[idx] = __float2bfloat16(fmaxf(fmaxf(v0, v1), fmaxf(v2, v3)));
}

// gT[b][v][p] = max 2x2 of pgf[b,h,w,128+v]
__global__ __launch_bounds__(256) void k_pool_gT(const __hip_bfloat16* __restrict__ pg,
                                                 __hip_bfloat16* __restrict__ gT) {
  __shared__ __hip_bfloat16 t[64][65];
  const int p0 = blockIdx.x * 64, v0 = blockIdx.y * 64, b = blockIdx.z;
#pragma unroll
  for (int it = 0; it < 16; ++it) {
    int li = it * 256 + threadIdx.x;
    int pp = li >> 6, v = li & 63;
    int p = p0 + pp;
    int ph = p >> 5, pw = p & 31;
    size_t base = ((size_t)b * 4096 + ph * 128 + pw * 2) * kNP + 128 + v0 + v;
    float mv = fmaxf(
        fmaxf(__bfloat162float(pg[base]), __bfloat162float(pg[base + kNP])),
        fmaxf(__bfloat162float(pg[base + kNP * 64]), __bfloat162float(pg[base + kNP * 64 + kNP])));
    t[pp][v] = __float2bfloat16(mv);
  }
  __syncthreads();
#pragma unroll
  for (int it = 0; it < 16; ++it) {
    int li = it * 256 + threadIdx.x;
    int v = li >> 6, p = li & 63;
    gT[((size_t)b * 256 + v0 + v) * 1024 + p0 + p] = t[p][v];
  }
}

// ---- fused attention, barrier-free: 32 Q rows/block, 8 waves, 512 thr ----
// P1: wave w owns keys [w*128, +128): Q/K frags DIRECT from global, no LDS, no
//     barriers; scores in regs (sc[2][8][4] = 64 f32).
// softmax: cross-wave via small LDS (pred/rowstat), 4 barriers.
// P write: [32 q][1024 k] bf16 LDS, row 2048B, slot swizzle oct^(row&15); 1 barrier.
// PV: wave w owns v in [w*32, +32): G frags DIRECT from global (L2-resident via
//     XCD pinning), A-frags from LDS P; 2-deep register prefetch; no barriers.
__global__ __launch_bounds__(512, 4) void k_fattn(
    const __hip_bfloat16* __restrict__ pgf,   // [B*4096][384], theta cols 0..63
    const __hip_bfloat16* __restrict__ phip,  // [B][1024][64]
    const __hip_bfloat16* __restrict__ gT,    // [B][256][1024]
    __hip_bfloat16* __restrict__ O) {         // [B][4096][256]
  __shared__ __align__(16) char smem[65536 + 1024 + 128];
  char* P = smem;                                   // [32][1024] bf16 swizzled
  float* pred = (float*)(smem + 65536);             // [32][8]
  float* rowstat = (float*)(smem + 65536 + 1024);   // [32]

  const int tid = threadIdx.x, wid = tid >> 6, lane = tid & 63;
  const int m = lane & 15, quad = lane >> 4;
  const int bid = blockIdx.x;
  const int b = bid & 7;          // batch -> XCD (round-robin assignment)
  const int q0 = (bid >> 3) * 32;

  // Q A-frags direct: aq[i][t] = Q[i*16+m][t*32 + quad*8 ..+8]
  short8 aq[2][2];
  const __hip_bfloat16* qb = pgf + (size_t)(b * kHW + q0) * kNP;
#pragma unroll
  for (int i = 0; i < 2; ++i)
#pragma unroll
    for (int t = 0; t < 2; ++t)
      aq[i][t] = *(const short8*)(qb + (size_t)(i * 16 + m) * kNP + t * 32 + quad * 8);

  // ---- P1: QK^T over this wave's 128 keys, direct K B-frags, 2-deep prefetch
  const __hip_bfloat16* kbp = phip + ((size_t)b * kP + wid * 128) * 64;
  float4v sc[2][8] = {};
  short8 kf[2][2];
#pragma unroll
  for (int t = 0; t < 2; ++t)
    kf[0][t] = *(const short8*)(kbp + (size_t)m * 64 + t * 32 + quad * 8);
#pragma unroll
  for (int c = 0; c < 8; ++c) {
    if (c < 7) {
#pragma unroll
      for (int t = 0; t < 2; ++t)
        kf[(c + 1) & 1][t] =
            *(const short8*)(kbp + (size_t)((c + 1) * 16 + m) * 64 + t * 32 + quad * 8);
    }
#pragma unroll
    for (int t = 0; t < 2; ++t)
#pragma unroll
      for (int i = 0; i < 2; ++i) sc[i][c] = mfma16(aq[i][t], kf[c & 1][t], sc[i][c]);
  }
  // lane (quad,m): sc[i][c][r] = S[q = i*16+quad*4+r][key = wid*128 + c*16 + m]

  // ---- softmax (exact; P unnormalized, 1/sum folded into epilogue) ----
  float mx[2][4];
#pragma unroll
  for (int i = 0; i < 2; ++i)
#pragma unroll
    for (int r = 0; r < 4; ++r) {
      float v = sc[i][0][r];
#pragma unroll
      for (int s = 1; s < 8; ++s) v = fmaxf(v, sc[i][s][r]);
#pragma unroll
      for (int d = 1; d < 16; d <<= 1) v = fmaxf(v, __shfl_xor(v, d));
      mx[i][r] = v;
    }
  if (m == 0) {
#pragma unroll
    for (int i = 0; i < 2; ++i)
#pragma unroll
      for (int r = 0; r < 4; ++r) pred[(i * 16 + quad * 4 + r) * 8 + wid] = mx[i][r];
  }
  __syncthreads();
  if (tid < 32) {
    float v = pred[tid * 8];
#pragma unroll
    for (int w = 1; w < 8; ++w) v = fmaxf(v, pred[tid * 8 + w]);
    rowstat[tid] = v;
  }
  __syncthreads();
  float sm[2][4];
#pragma unroll
  for (int i = 0; i < 2; ++i)
#pragma unroll
    for (int r = 0; r < 4; ++r) {
      const float rm = rowstat[i * 16 + quad * 4 + r];
      float s = 0.f;
#pragma unroll
      for (int ss = 0; ss < 8; ++ss) {
        float e = __expf(sc[i][ss][r] - rm);
        sc[i][ss][r] = e;
        s += e;
      }
#pragma unroll
      for (int d = 1; d < 16; d <<= 1) s += __shfl_xor(s, d);
      sm[i][r] = s;
    }
  __syncthreads();
  if (m == 0) {
#pragma unroll
    for (int i = 0; i < 2; ++i)
#pragma unroll
      for (int r = 0; r < 4; ++r) pred[(i * 16 + quad * 4 + r) * 8 + wid] = sm[i][r];
  }
  __syncthreads();
  if (tid < 32) {
    float s = 0.f;
#pragma unroll
    for (int w = 0; w < 8; ++w) s += pred[tid * 8 + w];
    rowstat[tid] = 1.f / s;
  }

  // ---- write P (unnormalized exp) to LDS, swizzle oct^(row&15), row=2048B ----
#pragma unroll
  for (int i = 0; i < 2; ++i)
#pragma unroll
    for (int c = 0; c < 8; ++c)
#pragma unroll
      for (int r = 0; r < 4; ++r) {
        const int row = i * 16 + quad * 4 + r;
        const int key = wid * 128 + c * 16 + m;
        const int oct = (key >> 3) ^ (row & 15);
        *(__hip_bfloat16*)(P + row * 2048 + oct * 16 + (key & 7) * 2) =
            __float2bfloat16(sc[i][c][r]);
      }
  __syncthreads();  // P + rowstat visible to all waves

  // ---- PV: stream G direct from global, A-frags from LDS P, no barriers ----
  const __hip_bfloat16* gb = gT + ((size_t)b * kCV + wid * 32) * kP;
  float4v oc[2][2] = {};
  short8 gf[2][2], af[2][2];
#pragma unroll
  for (int j = 0; j < 2; ++j)
    gf[0][j] = *(const short8*)(gb + (size_t)(j * 16 + m) * kP + quad * 8);
#pragma unroll
  for (int i = 0; i < 2; ++i) {
    const int row = i * 16 + m;
    af[0][i] = *(const short8*)(P + row * 2048 + ((quad ^ (row & 15)) * 16));
  }
#pragma unroll
  for (int cp = 0; cp < 32; ++cp) {
    const int cur = cp & 1;
    if (cp < 31) {
      const int p0n = (cp + 1) * 32;
#pragma unroll
      for (int j = 0; j < 2; ++j)
        gf[cur ^ 1][j] = *(const short8*)(gb + (size_t)(j * 16 + m) * kP + p0n + quad * 8);
#pragma unroll
      for (int i = 0; i < 2; ++i) {
        const int row = i * 16 + m;
        const int oct = ((cp + 1) * 4 + quad) ^ (row & 15);
        af[cur ^ 1][i] = *(const short8*)(P + row * 2048 + oct * 16);
      }
    }
#pragma unroll
    for (int i = 0; i < 2; ++i)
#pragma unroll
      for (int j = 0; j < 2; ++j) oc[i][j] = mfma16(af[cur][i], gf[cur][j], oc[i][j]);
  }

  const float r0v = rowstat[quad * 4 + 0];  // rows for i=0 block handled below
#pragma unroll
  for (int i = 0; i < 2; ++i)
#pragma unroll
    for (int j = 0; j < 2; ++j)
#pragma unroll
      for (int r = 0; r < 4; ++r) {
        const int row = i * 16 + quad * 4 + r;
        O[((size_t)b * kHW + q0 + row) * kCV + wid * 32 + j * 16 + m] =
            __float2bfloat16(oc[i][j][r] * rowstat[row]);
      }
  (void)r0v;
}

// ---- out = x + gamma * (O @ w_o), tile 128x128, dbuf, swizzled ----
__global__ __launch_bounds__(256) void k_out(const __hip_bfloat16* __restrict__ A,
                                             const __hip_bfloat16* __restrict__ Bw,
                                             const float* __restrict__ x,
                                             const float* __restrict__ gamma,
                                             float* __restrict__ out) {
  __shared__ __align__(16) char smem[4 * 16384];  // As[2] then Bs[2]
  const int tid = threadIdx.x, wid = tid >> 6, lane = tid & 63;
  const int m = lane & 15, quad = lane >> 4;
  const int row0 = blockIdx.x * 128, col0 = blockIdx.y * 128;
  const int wm = (wid >> 1) * 64, wn = (wid & 1) * 64;
  float4v acc[4][4] = {};
  auto stage = [&](int t, int buf) {
    const int kc = t * 64;
#pragma unroll
    for (int u = 0; u < 4; ++u) {
      const int r0 = (wid * 4 + u) * 8;
      const int row = r0 + (lane >> 3);
      const int og = (lane & 7) ^ (row & 7);
      gll16(A + (size_t)(row0 + row) * 256 + kc + og * 8, smem + buf * 16384 + r0 * 128);
      gll16(Bw + (size_t)(col0 + row) * 256 + kc + og * 8,
            smem + 32768 + buf * 16384 + r0 * 128);
    }
  };
  stage(0, 0);
  __syncthreads();
#pragma unroll
  for (int t = 0; t < 4; ++t) {
    if (t < 3) stage(t + 1, (t + 1) & 1);
    const char* Ab = smem + (t & 1) * 16384;
    const char* Bb = smem + 32768 + (t & 1) * 16384;
    __builtin_amdgcn_s_setprio(1);
#pragma unroll
    for (int kk = 0; kk < 64; kk += 32) {
      const int oct = (kk >> 3) + quad;
      short8 af[4], bf[4];
#pragma unroll
      for (int i = 0; i < 4; ++i) af[i] = *fragp(Ab, wm + i * 16 + m, oct);
#pragma unroll
      for (int j = 0; j < 4; ++j) bf[j] = *fragp(Bb, wn + j * 16 + m, oct);
#pragma unroll
      for (int i = 0; i < 4; ++i)
#pragma unroll
        for (int j = 0; j < 4; ++j) acc[i][j] = mfma16(af[i], bf[j], acc[i][j]);
    }
    __builtin_amdgcn_s_setprio(0);
    __syncthreads();
  }
  const float g = gamma[0];
#pragma unroll
  for (int i = 0; i < 4; ++i)
#pragma unroll
    for (int j = 0; j < 4; ++j) {
      const int cc = col0 + wn + j * 16 + m;
      const int rb = row0 + wm + i * 16 + quad * 4;
#pragma unroll
      for (int r = 0; r < 4; ++r) {
        const size_t idx = (size_t)(rb + r) * 512 + cc;
        out[idx] = x[idx] + g * acc[i][j][r];
      }
    }
}

extern "C" void kernel_launch(void* const* d_in, const int* in_sizes, int n_in,
                              void* d_out, int out_size, void* d_ws, size_t ws_size,
                              hipStream_t stream) {
  (void)in_sizes; (void)n_in; (void)out_size; (void)ws_size;
  const float* x     = (const float*)d_in[0];
  const float* wt    = (const float*)d_in[1];
  const float* wphi  = (const float*)d_in[2];
  const float* wg    = (const float*)d_in[3];
  const float* wo    = (const float*)d_in[4];
  const float* gamma = (const float*)d_in[5];
  float* out = (float*)d_out;

  char* ws = (char*)d_ws;
  __hip_bfloat16* wAll = (__hip_bfloat16*)(ws);              //    393,216
  __hip_bfloat16* woT  = (__hip_bfloat16*)(ws + 393216);     //    262,144
  __hip_bfloat16* pgf  = (__hip_bfloat16*)(ws + 655360);     // 25,165,824
  __hip_bfloat16* phip = (__hip_bfloat16*)(ws + 25821184);   //  1,048,576
  __hip_bfloat16* gT   = (__hip_bfloat16*)(ws + 26869760);   //  4,194,304
  __hip_bfloat16* O    = (__hip_bfloat16*)(ws + 31064064);   // 16,777,216  (total 47.8MB)

  k_pack_w<<<1280, 256, 0, stream>>>(wt, wphi, wg, wo, wAll, woT);
  k_proj<<<512, 256, 0, stream>>>(x, wAll, pgf);
  k_pool_phi<<<2048, 256, 0, stream>>>(pgf, phip);
  k_pool_gT<<<dim3(16, 4, 8), 256, 0, stream>>>(pgf, gT);
  k_fattn<<<dim3(kHW / 32 * kB), 512, 0, stream>>>(pgf, phip, gT, O);
  k_out<<<dim3(256, 4), 256, 0, stream>>>(O, woT, x, gamma, out);
}

// Round 4
// 234.940 us; speedup vs baseline: 1.0924x; 1.0924x over previous
//
#include <hip/hip_runtime.h>
#include <hip/hip_bf16.h>
#include <cstddef>
#include <cstdint>

// SelfAttn (SAGAN) — Round 9: QBLK=64 fattn (halves G/K L2 re-reads, the cost
// invariant across R5-R8). 1024 thr / 16 waves; P1 waves split 2D (8 key-slices
// x 2 q-halves, sc=64 VGPR); P[64][1024] bf16 in LDS (128KB, 1 blk/CU, 16 waves
// resident); PV barrier-free direct-G streaming, wave owns 16 v-rows.

typedef __attribute__((ext_vector_type(8))) short short8;
typedef __attribute__((ext_vector_type(4))) float float4v;

namespace {
constexpr int kB = 8, kC = 512, kCK = 64, kCV = 256, kHW = 4096, kP = 1024;
constexpr int kNP = 384;  // packed projection width [theta|phi|g]
}

__device__ __forceinline__ void gll16(const void* g, void* l) {
  __builtin_amdgcn_global_load_lds((uint32_t __attribute__((address_space(1)))*)g,
                                   (uint32_t __attribute__((address_space(3)))*)l,
                                   16, 0, 0);
}
__device__ __forceinline__ float4v mfma16(short8 a, short8 b, float4v c) {
  return __builtin_amdgcn_mfma_f32_16x16x32_bf16(a, b, c, 0, 0, 0);
}
// bf16 tile row = 128B (8 octs of 16B), slot swizzle oct ^ (row&7)
__device__ __forceinline__ const short8* fragp(const char* tile, int row, int oct) {
  return (const short8*)(tile + row * 128 + ((oct ^ (row & 7)) * 16));
}

// pack weights: wAll[384][512] = [theta|phi|g]^T; woT[512][256]
__global__ __launch_bounds__(256) void k_pack_w(
    const float* __restrict__ wt, const float* __restrict__ wphi,
    const float* __restrict__ wg, const float* __restrict__ wo,
    __hip_bfloat16* __restrict__ wAll, __hip_bfloat16* __restrict__ woT) {
  int idx = blockIdx.x * 256 + threadIdx.x;  // 327680
  if (idx < 196608) {
    int n = idx >> 9, k = idx & 511;
    float v = (n < 64) ? wt[k * 64 + n]
            : (n < 128) ? wphi[k * 64 + (n - 64)]
                        : wg[k * 256 + (n - 128)];
    wAll[idx] = __float2bfloat16(v);
  } else {
    int t = idx - 196608;
    int n = t >> 8, k = t & 255;
    woT[t] = __float2bfloat16(wo[k * 512 + n]);
  }
}

// ---- proj: pgf[32768][384] = bf16(x) @ wAll^T, A fp32 read direct, tile 64x384 ----
__global__ __launch_bounds__(256) void k_proj(const float* __restrict__ x,
                                              const __hip_bfloat16* __restrict__ wAll,
                                              __hip_bfloat16* __restrict__ pgf) {
  __shared__ __align__(16) char smem[16384 + 49152];
  char* As = smem;           // fp32 [64 rows][16 sq of 16B], swizzle sq^(row&15)
  char* Bs = smem + 16384;   // bf16 [384 rows][8 oct], swizzle oct^(row&7)
  const int tid = threadIdx.x, wid = tid >> 6, lane = tid & 63;
  const int m = lane & 15, quad = lane >> 4;
  const int row0 = blockIdx.x * 64;
  const int wm = (wid >> 1) * 32, wn = (wid & 1) * 192;
  float4v acc[2][12] = {};
  for (int kc = 0; kc < 512; kc += 64) {
#pragma unroll
    for (int u = 0; u < 4; ++u) {  // A: region = 4 rows x 16 sq (1KB)
      const int r0 = (wid * 4 + u) * 4;
      const int row = r0 + (lane >> 4);
      const int sqg = (lane & 15) ^ (row & 15);
      gll16(x + (size_t)(row0 + row) * 512 + kc + sqg * 4, As + r0 * 256);
    }
#pragma unroll
    for (int u = 0; u < 12; ++u) {  // B: region = 8 rows x 8 oct (1KB)
      const int r0 = (wid * 12 + u) * 8;
      const int row = r0 + (lane >> 3);
      const int og = (lane & 7) ^ (row & 7);
      gll16(wAll + (size_t)row * 512 + kc + og * 8, Bs + r0 * 128);
    }
    __syncthreads();
#pragma unroll
    for (int kk = 0; kk < 64; kk += 32) {
      short8 af[2];
#pragma unroll
      for (int i = 0; i < 2; ++i) {
        const int row = wm + i * 16 + m;
        const int sq0 = (kk >> 2) + quad * 2;
        float4v lo = *(const float4v*)(As + row * 256 + ((sq0 ^ m) * 16));
        float4v hi = *(const float4v*)(As + row * 256 + (((sq0 + 1) ^ m) * 16));
        short8 a;
        a[0] = __builtin_bit_cast(short, __float2bfloat16(lo[0]));
        a[1] = __builtin_bit_cast(short, __float2bfloat16(lo[1]));
        a[2] = __builtin_bit_cast(short, __float2bfloat16(lo[2]));
        a[3] = __builtin_bit_cast(short, __float2bfloat16(lo[3]));
        a[4] = __builtin_bit_cast(short, __float2bfloat16(hi[0]));
        a[5] = __builtin_bit_cast(short, __float2bfloat16(hi[1]));
        a[6] = __builtin_bit_cast(short, __float2bfloat16(hi[2]));
        a[7] = __builtin_bit_cast(short, __float2bfloat16(hi[3]));
        af[i] = a;
      }
      const int oct = (kk >> 3) + quad;
#pragma unroll
      for (int j = 0; j < 12; ++j) {
        short8 bf = *fragp(Bs, wn + j * 16 + m, oct);
#pragma unroll
        for (int i = 0; i < 2; ++i) acc[i][j] = mfma16(af[i], bf, acc[i][j]);
      }
    }
    __syncthreads();
  }
#pragma unroll
  for (int i = 0; i < 2; ++i)
#pragma unroll
    for (int j = 0; j < 12; ++j)
#pragma unroll
      for (int r = 0; r < 4; ++r)
        pgf[(size_t)(row0 + wm + i * 16 + quad * 4 + r) * 384 + wn + j * 16 + m] =
            __float2bfloat16(acc[i][j][r]);
}

// phi_p[b][p][c] = max 2x2 of pgf[b,h,w,64+c]
__global__ __launch_bounds__(256) void k_pool_phi(const __hip_bfloat16* __restrict__ pg,
                                                  __hip_bfloat16* __restrict__ phi_p) {
  int idx = blockIdx.x * 256 + threadIdx.x;  // 524288
  int c = idx & 63;
  int p = (idx >> 6) & 1023;
  int b = idx >> 16;
  int ph = p >> 5, pw = p & 31;
  size_t base = ((size_t)b * 4096 + ph * 128 + pw * 2) * kNP + 64 + c;
  float v0 = __bfloat162float(pg[base]);
  float v1 = __bfloat162float(pg[base + kNP]);
  float v2 = __bfloat162float(pg[base + kNP * 64]);
  float v3 = __bfloat162float(pg[base + kNP * 64 + kNP]);
  phi_p[idx] = __float2bfloat16(fmaxf(fmaxf(v0, v1), fmaxf(v2, v3)));
}

// gT[b][v][p] = max 2x2 of pgf[b,h,w,128+v]
__global__ __launch_bounds__(256) void k_pool_gT(const __hip_bfloat16* __restrict__ pg,
                                                 __hip_bfloat16* __restrict__ gT) {
  __shared__ __hip_bfloat16 t[64][65];
  const int p0 = blockIdx.x * 64, v0 = blockIdx.y * 64, b = blockIdx.z;
#pragma unroll
  for (int it = 0; it < 16; ++it) {
    int li = it * 256 + threadIdx.x;
    int pp = li >> 6, v = li & 63;
    int p = p0 + pp;
    int ph = p >> 5, pw = p & 31;
    size_t base = ((size_t)b * 4096 + ph * 128 + pw * 2) * kNP + 128 + v0 + v;
    float mv = fmaxf(
        fmaxf(__bfloat162float(pg[base]), __bfloat162float(pg[base + kNP])),
        fmaxf(__bfloat162float(pg[base + kNP * 64]), __bfloat162float(pg[base + kNP * 64 + kNP])));
    t[pp][v] = __float2bfloat16(mv);
  }
  __syncthreads();
#pragma unroll
  for (int it = 0; it < 16; ++it) {
    int li = it * 256 + threadIdx.x;
    int v = li >> 6, p = li & 63;
    gT[((size_t)b * 256 + v0 + v) * 1024 + p0 + p] = t[p][v];
  }
}

// ---- fused attention, QBLK=64: 1024 thr / 16 waves, 1 block/CU ----
// P1: wave (qh=wid&1, kw=wid>>1) computes S[qh*32..+32)[kw*128..+128); Q/K
//     direct-from-global 16B frags, no barriers; sc[2][8][4] = 64 VGPR.
// softmax: cross-wave via pred[64][8]/rowstat[64] LDS, exact, 1/sum in epilogue.
// P: [64 q][1024 k] bf16 LDS, row 2048B, 16B-slot swizzle (oct&15)^(row&15).
// PV: wave owns v-rows [wid*16,+16); G streamed direct from global (L2-resident
//     via XCD pinning), A-frags from LDS P; 2-deep G prefetch; no barriers.
__global__ __launch_bounds__(1024) void k_fattn(
    const __hip_bfloat16* __restrict__ pgf,   // [B*4096][384], theta cols 0..63
    const __hip_bfloat16* __restrict__ phip,  // [B][1024][64]
    const __hip_bfloat16* __restrict__ gT,    // [B][256][1024]
    __hip_bfloat16* __restrict__ O) {         // [B][4096][256]
  __shared__ __align__(16) char smem[131072 + 2048 + 256];
  char* P = smem;                                    // [64][1024] bf16 swizzled
  float* pred = (float*)(smem + 131072);             // [64][8]
  float* rowstat = (float*)(smem + 131072 + 2048);   // [64]

  const int tid = threadIdx.x, wid = tid >> 6, lane = tid & 63;
  const int m = lane & 15, quad = lane >> 4;
  const int bid = blockIdx.x;
  const int b = bid & 7;           // batch -> XCD (round-robin assignment)
  const int q0 = (bid >> 3) * 64;
  const int qh = wid & 1;          // q-half (32 rows) this wave covers in P1
  const int kw = wid >> 1;         // key-slice (128 keys) this wave covers in P1

  // Q A-frags direct: aq[i][t] = Q[qh*32 + i*16 + m][t*32 + quad*8 ..+8]
  short8 aq[2][2];
  const __hip_bfloat16* qb = pgf + (size_t)(b * kHW + q0 + qh * 32) * kNP;
#pragma unroll
  for (int i = 0; i < 2; ++i)
#pragma unroll
    for (int t = 0; t < 2; ++t)
      aq[i][t] = *(const short8*)(qb + (size_t)(i * 16 + m) * kNP + t * 32 + quad * 8);

  // ---- P1: QK^T over this wave's 128 keys, direct K B-frags, 2-deep prefetch
  const __hip_bfloat16* kbp = phip + ((size_t)b * kP + kw * 128) * 64;
  float4v sc[2][8] = {};
  short8 kf[2][2];
#pragma unroll
  for (int t = 0; t < 2; ++t)
    kf[0][t] = *(const short8*)(kbp + (size_t)m * 64 + t * 32 + quad * 8);
#pragma unroll
  for (int c = 0; c < 8; ++c) {
    if (c < 7) {
#pragma unroll
      for (int t = 0; t < 2; ++t)
        kf[(c + 1) & 1][t] =
            *(const short8*)(kbp + (size_t)((c + 1) * 16 + m) * 64 + t * 32 + quad * 8);
    }
#pragma unroll
    for (int t = 0; t < 2; ++t)
#pragma unroll
      for (int i = 0; i < 2; ++i) sc[i][c] = mfma16(aq[i][t], kf[c & 1][t], sc[i][c]);
  }
  // lane (quad,m): sc[i][c][r] = S[q = qh*32+i*16+quad*4+r][key = kw*128+c*16+m]

  // ---- softmax (exact; P unnormalized, 1/sum folded into epilogue) ----
  float mx[2][4];
#pragma unroll
  for (int i = 0; i < 2; ++i)
#pragma unroll
    for (int r = 0; r < 4; ++r) {
      float v = sc[i][0][r];
#pragma unroll
      for (int s = 1; s < 8; ++s) v = fmaxf(v, sc[i][s][r]);
#pragma unroll
      for (int d = 1; d < 16; d <<= 1) v = fmaxf(v, __shfl_xor(v, d));
      mx[i][r] = v;
    }
  if (m == 0) {
#pragma unroll
    for (int i = 0; i < 2; ++i)
#pragma unroll
      for (int r = 0; r < 4; ++r)
        pred[(qh * 32 + i * 16 + quad * 4 + r) * 8 + kw] = mx[i][r];
  }
  __syncthreads();
  if (tid < 64) {
    float v = pred[tid * 8];
#pragma unroll
    for (int w = 1; w < 8; ++w) v = fmaxf(v, pred[tid * 8 + w]);
    rowstat[tid] = v;
  }
  __syncthreads();
  float sm[2][4];
#pragma unroll
  for (int i = 0; i < 2; ++i)
#pragma unroll
    for (int r = 0; r < 4; ++r) {
      const float rm = rowstat[qh * 32 + i * 16 + quad * 4 + r];
      float s = 0.f;
#pragma unroll
      for (int ss = 0; ss < 8; ++ss) {
        float e = __expf(sc[i][ss][r] - rm);
        sc[i][ss][r] = e;
        s += e;
      }
#pragma unroll
      for (int d = 1; d < 16; d <<= 1) s += __shfl_xor(s, d);
      sm[i][r] = s;
    }
  if (m == 0) {
#pragma unroll
    for (int i = 0; i < 2; ++i)
#pragma unroll
      for (int r = 0; r < 4; ++r)
        pred[(qh * 32 + i * 16 + quad * 4 + r) * 8 + kw] = sm[i][r];
  }
  __syncthreads();
  if (tid < 64) {
    float s = 0.f;
#pragma unroll
    for (int w = 0; w < 8; ++w) s += pred[tid * 8 + w];
    rowstat[tid] = 1.f / s;
  }
  __syncthreads();

  // ---- write P (unnormalized exp) to LDS; row=2048B, swizzle (oct&15)^(row&15)
#pragma unroll
  for (int i = 0; i < 2; ++i)
#pragma unroll
    for (int c = 0; c < 8; ++c)
#pragma unroll
      for (int r = 0; r < 4; ++r) {
        const int row = qh * 32 + i * 16 + quad * 4 + r;
        const int key = kw * 128 + c * 16 + m;
        const int oct = key >> 3;
        const int oc2 = (oct & 0x70) | ((oct & 15) ^ (row & 15));
        *(__hip_bfloat16*)(P + row * 2048 + oc2 * 16 + (key & 7) * 2) =
            __float2bfloat16(sc[i][c][r]);
      }
  __syncthreads();  // P visible to all waves

  // ---- PV: wave owns v-rows [wid*16,+16); stream G direct, no barriers ----
  const __hip_bfloat16* gbase = gT + ((size_t)b * kCV + wid * 16 + m) * kP;
  float4v oc[4] = {};
  short8 gf[2];
  gf[0] = *(const short8*)(gbase + quad * 8);
#pragma unroll
  for (int cp = 0; cp < 32; ++cp) {
    const int cur = cp & 1;
    if (cp < 31) gf[cur ^ 1] = *(const short8*)(gbase + (cp + 1) * 32 + quad * 8);
    short8 af[4];
#pragma unroll
    for (int i = 0; i < 4; ++i) {
      const int row = i * 16 + m;
      const int oct = cp * 4 + quad;
      const int oc2 = (oct & 0x70) | ((oct & 15) ^ (row & 15));
      af[i] = *(const short8*)(P + row * 2048 + oc2 * 16);
    }
#pragma unroll
    for (int i = 0; i < 4; ++i) oc[i] = mfma16(af[i], gf[cur], oc[i]);
  }

#pragma unroll
  for (int i = 0; i < 4; ++i)
#pragma unroll
    for (int r = 0; r < 4; ++r) {
      const int row = i * 16 + quad * 4 + r;
      O[((size_t)b * kHW + q0 + row) * kCV + wid * 16 + m] =
          __float2bfloat16(oc[i][r] * rowstat[row]);
    }
}

// ---- out = x + gamma * (O @ w_o), tile 128x128, dbuf, swizzled ----
__global__ __launch_bounds__(256) void k_out(const __hip_bfloat16* __restrict__ A,
                                             const __hip_bfloat16* __restrict__ Bw,
                                             const float* __restrict__ x,
                                             const float* __restrict__ gamma,
                                             float* __restrict__ out) {
  __shared__ __align__(16) char smem[4 * 16384];  // As[2] then Bs[2]
  const int tid = threadIdx.x, wid = tid >> 6, lane = tid & 63;
  const int m = lane & 15, quad = lane >> 4;
  const int row0 = blockIdx.x * 128, col0 = blockIdx.y * 128;
  const int wm = (wid >> 1) * 64, wn = (wid & 1) * 64;
  float4v acc[4][4] = {};
  auto stage = [&](int t, int buf) {
    const int kc = t * 64;
#pragma unroll
    for (int u = 0; u < 4; ++u) {
      const int r0 = (wid * 4 + u) * 8;
      const int row = r0 + (lane >> 3);
      const int og = (lane & 7) ^ (row & 7);
      gll16(A + (size_t)(row0 + row) * 256 + kc + og * 8, smem + buf * 16384 + r0 * 128);
      gll16(Bw + (size_t)(col0 + row) * 256 + kc + og * 8,
            smem + 32768 + buf * 16384 + r0 * 128);
    }
  };
  stage(0, 0);
  __syncthreads();
#pragma unroll
  for (int t = 0; t < 4; ++t) {
    if (t < 3) stage(t + 1, (t + 1) & 1);
    const char* Ab = smem + (t & 1) * 16384;
    const char* Bb = smem + 32768 + (t & 1) * 16384;
    __builtin_amdgcn_s_setprio(1);
#pragma unroll
    for (int kk = 0; kk < 64; kk += 32) {
      const int oct = (kk >> 3) + quad;
      short8 af[4], bf[4];
#pragma unroll
      for (int i = 0; i < 4; ++i) af[i] = *fragp(Ab, wm + i * 16 + m, oct);
#pragma unroll
      for (int j = 0; j < 4; ++j) bf[j] = *fragp(Bb, wn + j * 16 + m, oct);
#pragma unroll
      for (int i = 0; i < 4; ++i)
#pragma unroll
        for (int j = 0; j < 4; ++j) acc[i][j] = mfma16(af[i], bf[j], acc[i][j]);
    }
    __builtin_amdgcn_s_setprio(0);
    __syncthreads();
  }
  const float g = gamma[0];
#pragma unroll
  for (int i = 0; i < 4; ++i)
#pragma unroll
    for (int j = 0; j < 4; ++j) {
      const int cc = col0 + wn + j * 16 + m;
      const int rb = row0 + wm + i * 16 + quad * 4;
#pragma unroll
      for (int r = 0; r < 4; ++r) {
        const size_t idx = (size_t)(rb + r) * 512 + cc;
        out[idx] = x[idx] + g * acc[i][j][r];
      }
    }
}

extern "C" void kernel_launch(void* const* d_in, const int* in_sizes, int n_in,
                              void* d_out, int out_size, void* d_ws, size_t ws_size,
                              hipStream_t stream) {
  (void)in_sizes; (void)n_in; (void)out_size; (void)ws_size;
  const float* x     = (const float*)d_in[0];
  const float* wt    = (const float*)d_in[1];
  const float* wphi  = (const float*)d_in[2];
  const float* wg    = (const float*)d_in[3];
  const float* wo    = (const float*)d_in[4];
  const float* gamma = (const float*)d_in[5];
  float* out = (float*)d_out;

  char* ws = (char*)d_ws;
  __hip_bfloat16* wAll = (__hip_bfloat16*)(ws);              //    393,216
  __hip_bfloat16* woT  = (__hip_bfloat16*)(ws + 393216);     //    262,144
  __hip_bfloat16* pgf  = (__hip_bfloat16*)(ws + 655360);     // 25,165,824
  __hip_bfloat16* phip = (__hip_bfloat16*)(ws + 25821184);   //  1,048,576
  __hip_bfloat16* gT   = (__hip_bfloat16*)(ws + 26869760);   //  4,194,304
  __hip_bfloat16* O    = (__hip_bfloat16*)(ws + 31064064);   // 16,777,216  (total 47.8MB)

  k_pack_w<<<1280, 256, 0, stream>>>(wt, wphi, wg, wo, wAll, woT);
  k_proj<<<512, 256, 0, stream>>>(x, wAll, pgf);
  k_pool_phi<<<2048, 256, 0, stream>>>(pgf, phip);
  k_pool_gT<<<dim3(16, 4, 8), 256, 0, stream>>>(pgf, gT);
  k_fattn<<<dim3(kHW / 64 * kB), 1024, 0, stream>>>(pgf, phip, gT, O);
  k_out<<<dim3(256, 4), 256, 0, stream>>>(O, woT, x, gamma, out);
}